// Round 3
// baseline (397.388 us; speedup 1.0000x reference)
//
#include <hip/hip_runtime.h>
#include <hip/hip_bf16.h>

typedef __attribute__((ext_vector_type(8))) short short8;
typedef __attribute__((ext_vector_type(4))) short short4v;
typedef __attribute__((ext_vector_type(4))) float f32x4;

static __device__ __forceinline__ unsigned short f2bf(float f) {
  unsigned int u = __float_as_uint(f);
  u += 0x7fffu + ((u >> 16) & 1u);
  return (unsigned short)(u >> 16);
}

static __device__ __forceinline__ unsigned pk2bf(float a, float b) {
  union { __hip_bfloat162 h; unsigned u; } v;
  v.h = __float22bfloat162_rn(make_float2(a, b));
  return v.u;
}

// ---------------- converts ----------------
__global__ void conv_bf16_kernel(const float* __restrict__ in,
                                 unsigned short* __restrict__ out, int n) {
  int i = (blockIdx.x * blockDim.x + threadIdx.x) * 4;
  if (i >= n) return;
  float4 v = *(const float4*)(in + i);
  short4v o;
  o[0] = (short)f2bf(v.x); o[1] = (short)f2bf(v.y);
  o[2] = (short)f2bf(v.z); o[3] = (short)f2bf(v.w);
  *(short4v*)(out + i) = o;
}

// W [K=1024,N=1024] fp32 -> Wt [N,K] bf16
__global__ void wtrans_kernel(const float* __restrict__ W,
                              unsigned short* __restrict__ Wt) {
  __shared__ float t[32][33];
  int n0 = blockIdx.x * 32, k0 = blockIdx.y * 32;
#pragma unroll
  for (int j = 0; j < 4; ++j)
    t[threadIdx.y + j * 8][threadIdx.x] =
        W[(size_t)(k0 + threadIdx.y + j * 8) * 1024 + n0 + threadIdx.x];
  __syncthreads();
#pragma unroll
  for (int j = 0; j < 4; ++j)
    Wt[(size_t)(n0 + threadIdx.y + j * 8) * 1024 + k0 + threadIdx.x] =
        f2bf(t[threadIdx.x][threadIdx.y + j * 8]);
}

__global__ void mask_kernel(const float* __restrict__ e, float* __restrict__ mb, int n) {
  int i = blockIdx.x * blockDim.x + threadIdx.x;
  if (i < n) mb[i] = (fabsf(e[i]) > 0.1f) ? 0.0f : -1e30f;
}

// ---------------- GEMM: C[M=8192,N=1024] = X @ Wt^T + bias ----------------
template <int MODE>
__global__ __launch_bounds__(256) void gemm128_kernel(
    const unsigned short* __restrict__ X, const unsigned short* __restrict__ Wt,
    const float* __restrict__ bias, void* __restrict__ outp) {
  const int K = 1024;
  __shared__ unsigned short Al[128 * 40];
  __shared__ unsigned short Bl[128 * 40];
  const int m0 = blockIdx.x * 128, n0 = blockIdx.y * 128;
  const int tid = threadIdx.x, lane = tid & 63, wid = tid >> 6;
  const int wr = wid >> 1, wc = wid & 1;
  const int g = lane >> 4, lr = lane & 15;
  const f32x4 fz = {0.f, 0.f, 0.f, 0.f};
  f32x4 acc[4][4];
#pragma unroll
  for (int i = 0; i < 4; i++)
#pragma unroll
    for (int j = 0; j < 4; j++) acc[i][j] = fz;
  const int srow = tid >> 2;
  const int skc = (tid & 3) * 8;

  for (int k0 = 0; k0 < K; k0 += 32) {
#pragma unroll
    for (int p = 0; p < 2; ++p) {
      int row = srow + p * 64;
      *(short8*)(Al + row * 40 + skc) =
          *(const short8*)(X + (size_t)(m0 + row) * K + k0 + skc);
      *(short8*)(Bl + row * 40 + skc) =
          *(const short8*)(Wt + (size_t)(n0 + row) * K + k0 + skc);
    }
    __syncthreads();
    short8 a[4], b[4];
#pragma unroll
    for (int i = 0; i < 4; i++)
      a[i] = *(const short8*)(Al + (wr * 64 + i * 16 + lr) * 40 + g * 8);
#pragma unroll
    for (int i = 0; i < 4; i++)
      b[i] = *(const short8*)(Bl + (wc * 64 + i * 16 + lr) * 40 + g * 8);
#pragma unroll
    for (int i = 0; i < 4; i++)
#pragma unroll
      for (int j = 0; j < 4; j++)
        acc[i][j] = __builtin_amdgcn_mfma_f32_16x16x32_bf16(a[i], b[j], acc[i][j], 0, 0, 0);
    __syncthreads();
  }

#pragma unroll
  for (int i = 0; i < 4; i++) {
    const int mrow0 = m0 + wr * 64 + i * 16 + g * 4;
#pragma unroll
    for (int j = 0; j < 4; j++) {
      const int ncol = n0 + wc * 64 + j * 16 + lr;
      const float bv = bias[ncol];
      if (MODE == 2) {
        float* out = (float*)outp;
#pragma unroll
        for (int e = 0; e < 4; e++)
          out[(size_t)(mrow0 + e) * 1024 + ncol] = acc[i][j][e] + bv;
      } else if (MODE == 0) {
        unsigned short* out = (unsigned short*)outp;
        const int h = ncol >> 6, dh = ncol & 63;
#pragma unroll
        for (int e = 0; e < 4; e++) {
          int mrow = mrow0 + e;
          int b_ = mrow >> 11, l = mrow & 2047;
          out[((size_t)(b_ * 16 + h) * 2048 + l) * 64 + dh] = f2bf(acc[i][j][e] + bv);
        }
      } else {
        unsigned short* out = (unsigned short*)outp;
        const int h = ncol >> 6, d = ncol & 63;
        const int b_ = mrow0 >> 11, s = mrow0 & 2047;
        short4v pk;
#pragma unroll
        for (int e = 0; e < 4; e++) pk[e] = (short)f2bf(acc[i][j][e] + bv);
        *(short4v*)(out + ((size_t)(b_ * 16 + h) * 64 + d) * 2048 + s) = pk;
      }
    }
  }
}

// ---------------- flash attention v3: barrier-free, LDS-free, fixed-max ----------------
// Qh,Kh: [B,H,S,64] bf16; Vt: [B,H,64,S] bf16; mb: [B,S] fp32 bias (0/-1e30)
// AO: [B*L, 1024] bf16.
// Grid: 2048 one-wave blocks (64 thr). Each wave owns 64 q-rows, streams all
// 32 K/V tiles from global (L2-resident per-XCD via bh-chunked swizzle).
// No __syncthreads, no LDS, no online max (scores bounded), denominator
// reduced once in the epilogue.
__global__ __launch_bounds__(64, 2) void attn_kernel(
    const unsigned short* __restrict__ Qh, const unsigned short* __restrict__ Kh,
    const unsigned short* __restrict__ Vt, const float* __restrict__ mb,
    unsigned short* __restrict__ AO) {
  const int S = 2048;
  // XCD-chunked bijective swizzle: 2048 blocks = 8 XCDs x 256; logical id is
  // bh-major so all 32 q-blocks of one bh land on one XCD (K/V L2 locality).
  int bx = blockIdx.x;
  int lid = (bx & 7) * 256 + (bx >> 3);
  const int bh = lid >> 5, qb = lid & 31;
  const int b_ = bh >> 4, h = bh & 15;
  const unsigned short* Qp = Qh + (size_t)bh * S * 64;
  const unsigned short* Kp = Kh + (size_t)bh * S * 64;
  const unsigned short* Vp = Vt + (size_t)bh * 64 * S;
  const float* mbp = mb + b_ * S;
  const int lane = threadIdx.x;
  const int g = lane >> 4, lr = lane & 15;
  const int qbase = qb * 64;
  const float c2 = 0.18033688011f;  // log2(e) / sqrt(64)
  const f32x4 fz = {0.f, 0.f, 0.f, 0.f};

  short8 qf[4][2];
#pragma unroll
  for (int qt = 0; qt < 4; qt++)
#pragma unroll
    for (int kh = 0; kh < 2; kh++)
      qf[qt][kh] = *(const short8*)(Qp + (size_t)(qbase + qt * 16 + lr) * 64 + kh * 32 + g * 8);

  f32x4 o[4][4];
  f32x4 psum[4];
#pragma unroll
  for (int qt = 0; qt < 4; qt++) {
    psum[qt] = fz;
#pragma unroll
    for (int t = 0; t < 4; t++) o[qt][t] = fz;
  }

  for (int s0 = 0; s0 < S; s0 += 64) {
    // K fragments: 8 x 16B global loads (L2-resident)
    short8 kf[4][2];
#pragma unroll
    for (int st = 0; st < 4; st++)
#pragma unroll
      for (int kh = 0; kh < 2; kh++)
        kf[st][kh] = *(const short8*)(Kp + (size_t)(s0 + st * 16 + lr) * 64 + kh * 32 + g * 8);
    // V^T fragments: 16 x 8B global loads
    short8 vf[4][2];
#pragma unroll
    for (int tt = 0; tt < 4; tt++)
#pragma unroll
      for (int ks = 0; ks < 2; ks++) {
        const unsigned short* base = Vp + (size_t)(tt * 16 + lr) * S + s0 + ks * 32;
        short4v lo = *(const short4v*)(base + g * 4);
        short4v hi = *(const short4v*)(base + 16 + g * 4);
        short8 v;
        v[0] = lo[0]; v[1] = lo[1]; v[2] = lo[2]; v[3] = lo[3];
        v[4] = hi[0]; v[5] = hi[1]; v[6] = hi[2]; v[7] = hi[3];
        vf[tt][ks] = v;
      }
    f32x4 mbv[4];
#pragma unroll
    for (int st = 0; st < 4; st++)
      mbv[st] = *(const f32x4*)(mbp + s0 + st * 16 + g * 4);

#pragma unroll
    for (int qt = 0; qt < 4; qt++) {
      f32x4 sc[4];
#pragma unroll
      for (int st = 0; st < 4; st++) {
        f32x4 a0 = __builtin_amdgcn_mfma_f32_16x16x32_bf16(kf[st][0], qf[qt][0], fz, 0, 0, 0);
        sc[st] = __builtin_amdgcn_mfma_f32_16x16x32_bf16(kf[st][1], qf[qt][1], a0, 0, 0, 0);
      }
      f32x4 pv[4];
#pragma unroll
      for (int st = 0; st < 4; st++) {
        f32x4 x = sc[st] * c2 + mbv[st];
#pragma unroll
        for (int e = 0; e < 4; e++) pv[st][e] = exp2f(x[e]);
      }
      psum[qt] += (pv[0] + pv[1]) + (pv[2] + pv[3]);
      union { short8 s8; unsigned u[4]; } pk0, pk1;
      pk0.u[0] = pk2bf(pv[0][0], pv[0][1]); pk0.u[1] = pk2bf(pv[0][2], pv[0][3]);
      pk0.u[2] = pk2bf(pv[1][0], pv[1][1]); pk0.u[3] = pk2bf(pv[1][2], pv[1][3]);
      pk1.u[0] = pk2bf(pv[2][0], pv[2][1]); pk1.u[1] = pk2bf(pv[2][2], pv[2][3]);
      pk1.u[2] = pk2bf(pv[3][0], pv[3][1]); pk1.u[3] = pk2bf(pv[3][2], pv[3][3]);
#pragma unroll
      for (int tt = 0; tt < 4; tt++) {
        o[qt][tt] = __builtin_amdgcn_mfma_f32_16x16x32_bf16(vf[tt][0], pk0.s8, o[qt][tt], 0, 0, 0);
        o[qt][tt] = __builtin_amdgcn_mfma_f32_16x16x32_bf16(vf[tt][1], pk1.s8, o[qt][tt], 0, 0, 0);
      }
    }
  }

#pragma unroll
  for (int qt = 0; qt < 4; qt++) {
    float l = (psum[qt][0] + psum[qt][1]) + (psum[qt][2] + psum[qt][3]);
    l += __shfl_xor(l, 16);
    l += __shfl_xor(l, 32);
    float inv = l > 0.f ? 1.f / l : 0.f;
    size_t row = (size_t)b_ * 2048 + qbase + qt * 16 + lr;
#pragma unroll
    for (int tt = 0; tt < 4; tt++) {
      short4v pkv;
#pragma unroll
      for (int i = 0; i < 4; i++) pkv[i] = (short)f2bf(o[qt][tt][i] * inv);
      *(short4v*)(AO + row * 1024 + h * 64 + tt * 16 + g * 4) = pkv;
    }
  }
}

// ---------------- launch ----------------
extern "C" void kernel_launch(void* const* d_in, const int* in_sizes, int n_in,
                              void* d_out, int out_size, void* d_ws, size_t ws_size,
                              hipStream_t stream) {
  const float* q_x = (const float*)d_in[0];
  const float* k_x = (const float*)d_in[1];
  const float* v_x = (const float*)d_in[2];
  const float* energy = (const float*)d_in[3];
  const float* Wq = (const float*)d_in[4];
  const float* bq = (const float*)d_in[5];
  const float* Wk = (const float*)d_in[6];
  const float* bk = (const float*)d_in[7];
  const float* Wv = (const float*)d_in[8];
  const float* bv = (const float*)d_in[9];
  const float* Wo = (const float*)d_in[10];
  const float* bo = (const float*)d_in[11];

  char* w = (char*)d_ws;
  auto take = [&](size_t bytes) {
    char* p = w;
    w += (bytes + 255) & ~(size_t)255;
    return p;
  };
  const size_t XB = (size_t)8192 * 1024 * 2;
  unsigned short* Xq = (unsigned short*)take(XB);
  unsigned short* Xk = (unsigned short*)take(XB);
  unsigned short* Xv = (unsigned short*)take(XB);
  unsigned short* Wtq = (unsigned short*)take((size_t)1024 * 1024 * 2);
  unsigned short* Wtk = (unsigned short*)take((size_t)1024 * 1024 * 2);
  unsigned short* Wtv = (unsigned short*)take((size_t)1024 * 1024 * 2);
  unsigned short* Wto = (unsigned short*)take((size_t)1024 * 1024 * 2);
  float* mb = (float*)take((size_t)4 * 2048 * 4);
  unsigned short* Qh = (unsigned short*)take(XB);
  unsigned short* Kh = (unsigned short*)take(XB);
  unsigned short* Vt = (unsigned short*)take(XB);
  unsigned short* AO = (unsigned short*)take(XB);

  const int NX = 8192 * 1024;
  conv_bf16_kernel<<<NX / 1024, 256, 0, stream>>>(q_x, Xq, NX);
  conv_bf16_kernel<<<NX / 1024, 256, 0, stream>>>(k_x, Xk, NX);
  conv_bf16_kernel<<<NX / 1024, 256, 0, stream>>>(v_x, Xv, NX);
  wtrans_kernel<<<dim3(32, 32), dim3(32, 8), 0, stream>>>(Wq, Wtq);
  wtrans_kernel<<<dim3(32, 32), dim3(32, 8), 0, stream>>>(Wk, Wtk);
  wtrans_kernel<<<dim3(32, 32), dim3(32, 8), 0, stream>>>(Wv, Wtv);
  wtrans_kernel<<<dim3(32, 32), dim3(32, 8), 0, stream>>>(Wo, Wto);
  mask_kernel<<<32, 256, 0, stream>>>(energy, mb, 8192);

  gemm128_kernel<0><<<dim3(64, 8), 256, 0, stream>>>(Xq, Wtq, bq, (void*)Qh);
  gemm128_kernel<0><<<dim3(64, 8), 256, 0, stream>>>(Xk, Wtk, bk, (void*)Kh);
  gemm128_kernel<1><<<dim3(64, 8), 256, 0, stream>>>(Xv, Wtv, bv, (void*)Vt);
  attn_kernel<<<2048, 64, 0, stream>>>(Qh, Kh, Vt, mb, AO);
  gemm128_kernel<2><<<dim3(64, 8), 256, 0, stream>>>(AO, Wto, bo, d_out);
}